// Round 1
// baseline (193.957 us; speedup 1.0000x reference)
//
#include <hip/hip_runtime.h>

// Problem constants (from reference): N=32768, H=6, W=8, C=14
constexpr int   kN          = 32768;
constexpr int   kCells      = 32768 * 6 * 8;          // 1,572,864 cells
constexpr int   kC          = 14;
constexpr int   kCellsBlk   = 256;                    // 1 thread = 1 cell
constexpr int   kBlocks     = kCells / kCellsBlk;     // 6144 (exact)
constexpr int   kFloatsBlk  = kCellsBlk * kC;         // 3584 floats / tensor / block
constexpr int   kVec4Blk    = kFloatsBlk / 4;         // 896 float4 (14336 B, 16-aligned)

constexpr float LAMBDA_COORD = 8.0f;
constexpr float LAMBDA_NOOBJ = 1.0f;
constexpr float LAMBDA_CLASS = 0.7f;
constexpr float EPS          = 1e-10f;

__device__ __forceinline__ float iou_box(float bx, float by, float bsw, float bsh,
                                         float gx, float gy, float gsw, float gsh) {
    float w1 = bsw * bsw, h1 = bsh * bsh;
    float w2 = gsw * gsw, h2 = gsh * gsh;
    float left  = fmaxf(bx - 0.5f * w1, gx - 0.5f * w2);
    float right = fminf(bx + 0.5f * w1, gx + 0.5f * w2);
    float top   = fmaxf(by - 0.5f * h1, gy - 0.5f * h2);
    float bot   = fminf(by + 0.5f * h1, gy + 0.5f * h2);
    float inter = fmaxf(right - left, 0.0f) * fmaxf(bot - top, 0.0f);
    float uni   = w1 * h1 + w2 * h2 - inter;
    return inter / (uni + EPS);
}

__global__ __launch_bounds__(256) void yolo_partial(const float* __restrict__ outp,
                                                    const float* __restrict__ gtp,
                                                    float* __restrict__ partial) {
    __shared__ float sO[kFloatsBlk];
    __shared__ float sG[kFloatsBlk];
    __shared__ float red[4];

    const int tid = threadIdx.x;
    const int blk = blockIdx.x;

    // Coalesced float4 stage: block chunk is 14336 B, 16 B aligned, grid-exact.
    const float4* go = reinterpret_cast<const float4*>(outp) + (long long)blk * kVec4Blk;
    const float4* gg = reinterpret_cast<const float4*>(gtp)  + (long long)blk * kVec4Blk;
    float4* lo = reinterpret_cast<float4*>(sO);
    float4* lg = reinterpret_cast<float4*>(sG);
#pragma unroll
    for (int k = 0; k < 4; ++k) {
        int i = tid + k * 256;
        if (i < kVec4Blk) { lo[i] = go[i]; lg[i] = gg[i]; }
    }
    __syncthreads();

    // Pull this cell's 14+14 floats into registers (constant indices only).
    float o[kC], g[kC];
#pragma unroll
    for (int c = 0; c < kC; ++c) {
        o[c] = sO[tid * kC + c];
        g[c] = sG[tid * kC + c];
    }

    float obj   = (g[4] > 0.0f) ? 1.0f : 0.0f;
    float noobj = 1.0f - obj;

    // IoU of both predicted boxes vs gt box 0
    float iou0 = iou_box(o[0], o[1], o[2], o[3], g[0], g[1], g[2], g[3]);
    float iou1 = iou_box(o[5], o[6], o[7], o[8], g[0], g[1], g[2], g[3]);
    bool  s1   = iou1 > iou0;              // jnp.argmax picks first on ties -> idx=1 iff iou1>iou0
    float max_iou = fmaxf(iou0, iou1);

    // Responsible / other selection via cndmask (no dynamic indexing)
    float pr0 = s1 ? o[5] : o[0];
    float pr1 = s1 ? o[6] : o[1];
    float pr2 = s1 ? o[7] : o[2];
    float pr3 = s1 ? o[8] : o[3];
    float pr4 = s1 ? o[9] : o[4];
    float po4 = s1 ? o[4] : o[9];          // other pred conf

    float gr0 = s1 ? g[5] : g[0];
    float gr1 = s1 ? g[6] : g[1];
    float gr2 = s1 ? g[7] : g[2];
    float gr3 = s1 ? g[8] : g[3];
    float gn4 = s1 ? g[4] : g[9];          // other gt conf

    float d4 = o[4] - g[4], d9 = o[9] - g[9];
    float no_loss = noobj * (d4 * d4 + d9 * d9);

    float dcf  = pr4 - max_iou;
    float conf = dcf * dcf;

    float l0 = pr0 - gr0, l1 = pr1 - gr1, l2 = pr2 - gr2, l3 = pr3 - gr3;
    float loc = l0 * l0 + l1 * l1 + l2 * l2 + l3 * l3;

    float dnb = po4 - gn4;
    float nbc = dnb * dnb;

    float cls = 0.0f;
#pragma unroll
    for (int c = 10; c < 14; ++c) { float d = o[c] - g[c]; cls += d * d; }

    float loss = LAMBDA_NOOBJ * no_loss +
                 obj * (conf + LAMBDA_COORD * loc + LAMBDA_NOOBJ * nbc + LAMBDA_CLASS * cls);

    // wave64 tree reduce
#pragma unroll
    for (int off = 32; off > 0; off >>= 1) loss += __shfl_down(loss, off, 64);
    if ((tid & 63) == 0) red[tid >> 6] = loss;
    __syncthreads();
    if (tid == 0) partial[blk] = red[0] + red[1] + red[2] + red[3];
}

__global__ __launch_bounds__(256) void yolo_final(const float* __restrict__ partial,
                                                  float* __restrict__ out) {
    __shared__ double red[4];
    double acc = 0.0;
    for (int i = threadIdx.x; i < kBlocks; i += 256) acc += (double)partial[i];
#pragma unroll
    for (int off = 32; off > 0; off >>= 1) acc += __shfl_down(acc, off, 64);
    int tid = threadIdx.x;
    if ((tid & 63) == 0) red[tid >> 6] = acc;
    __syncthreads();
    if (tid == 0) out[0] = (float)((red[0] + red[1] + red[2] + red[3]) * (1.0 / (double)kN));
}

extern "C" void kernel_launch(void* const* d_in, const int* in_sizes, int n_in,
                              void* d_out, int out_size, void* d_ws, size_t ws_size,
                              hipStream_t stream) {
    const float* outp = (const float*)d_in[0];   // output: (N,H,W,C) fp32
    const float* gtp  = (const float*)d_in[1];   // ground_truth: (N,H,W,C) fp32
    float* partial    = (float*)d_ws;            // 6144 floats = 24 KB scratch
    float* out        = (float*)d_out;

    yolo_partial<<<kBlocks, 256, 0, stream>>>(outp, gtp, partial);
    yolo_final<<<1, 256, 0, stream>>>(partial, out);
}